// Round 4
// baseline (2421.038 us; speedup 1.0000x reference)
//
#include <hip/hip_runtime.h>
#include <cstdint>
#include <cstddef>

typedef __bf16 bf16x8 __attribute__((ext_vector_type(8)));
typedef _Float16 f16x4 __attribute__((ext_vector_type(4)));
typedef _Float16 f16x2 __attribute__((ext_vector_type(2)));
typedef float f32x4 __attribute__((ext_vector_type(4)));

#define NTOK 16384
#define NMASK 16383
#define CDIM 512

__device__ __forceinline__ unsigned short f2bf(float f) {
  __bf16 b = (__bf16)f;
  return __builtin_bit_cast(unsigned short, b);
}
__device__ __forceinline__ float bf2f(unsigned short u) {
  return __builtin_bit_cast(float, (unsigned int)u << 16);
}
__device__ __forceinline__ f16x2 pk_f16(float a, float b) {
  return __builtin_bit_cast(f16x2, __builtin_amdgcn_cvt_pkrtz(a, b));
}

// async 16B global -> LDS (wave-uniform base + lane*16 semantics)
__device__ __forceinline__ void async16(unsigned short* lds, const unsigned short* g) {
  __builtin_amdgcn_global_load_lds(
      (__attribute__((address_space(1))) void*)(g),
      (__attribute__((address_space(3))) void*)(lds), 16, 0, 0);
}

// ---------------- fp32 -> bf16 conversion (weights) ----------------
__global__ void st_cvt_bf16(const float4* __restrict__ src, ushort4* __restrict__ dst, int n4) {
  int i = blockIdx.x * blockDim.x + threadIdx.x;
  int stride = gridDim.x * blockDim.x;
  for (; i < n4; i += stride) {
    float4 f = src[i];
    ushort4 o;
    o.x = f2bf(f.x); o.y = f2bf(f.y); o.z = f2bf(f.z); o.w = f2bf(f.w);
    dst[i] = o;
  }
}

// ---------------- h = feats @ in_w^T + in_b + pos_embed ----------------
__global__ __launch_bounds__(512) void st_embed(
    const float* __restrict__ feats, const int* __restrict__ coords,
    const float* __restrict__ in_w, const float* __restrict__ in_b,
    float* __restrict__ h) {
  int n = blockIdx.x;
  int c = threadIdx.x;
  float acc = in_b[c];
  const float* fr = feats + n * 8;
  const float* wr = in_w + c * 8;
#pragma unroll
  for (int k = 0; k < 8; k++) acc += fr[k] * wr[k];
  if (c < 510) {
    int g = c / 170;
    int cc = c - g * 170;
    int j = (cc < 85) ? cc : (cc - 85);
    float freq = exp2f(-0.15632603f * (float)j);  // 1/10000^(j/85)
    float o = (float)coords[n * 3 + g] * freq;
    acc += (cc < 85) ? sinf(o) : cosf(o);
  }
  h[(size_t)n * CDIM + c] = acc;
}

// ---------------- t-embedding -> c vector (512) ----------------
__global__ __launch_bounds__(512) void st_tembed1(
    const float* __restrict__ tptr,
    const float* __restrict__ w1, const float* __restrict__ b1,
    const float* __restrict__ w2, const float* __restrict__ b2,
    float* __restrict__ cbuf) {
  __shared__ float s_emb[256];
  __shared__ float s_h[512];
  int tid = threadIdx.x;
  float t = tptr[0];
  if (tid < 256) {
    int j = tid & 127;
    float fr = exp2f(-0.10381025f * (float)j);  // exp(-ln(1e4)*j/128)
    float a = t * fr;
    s_emb[tid] = (tid < 128) ? cosf(a) : sinf(a);
  }
  __syncthreads();
  float acc = b1[tid];
  const float* w1r = w1 + (size_t)tid * 256;
  for (int j = 0; j < 256; j++) acc += s_emb[j] * w1r[j];
  s_h[tid] = acc / (1.0f + exp2f(-1.44269504f * acc));  // silu
  __syncthreads();
  float acc2 = b2[tid];
  const float* w2r = w2 + (size_t)tid * 512;
  for (int j = 0; j < 512; j++) acc2 += s_h[j] * w2r[j];
  cbuf[tid] = acc2;
}

// ---------------- mod[l] = silu(c) @ ada_w[l]^T + ada_b[l] ----------------
__global__ __launch_bounds__(256) void st_tembed2(
    const float* __restrict__ cbuf, const float* __restrict__ ada_w,
    const float* __restrict__ ada_b, float* __restrict__ mod) {
  __shared__ float s_sc[512];
  int tid = threadIdx.x;
  for (int i = tid; i < 512; i += 256) {
    float v = cbuf[i];
    s_sc[i] = v / (1.0f + exp2f(-1.44269504f * v));
  }
  __syncthreads();
  int l = blockIdx.x / 12;
  int o = (blockIdx.x % 12) * 256 + tid;
  size_t idx = (size_t)l * 3072 + o;
  float acc = ada_b[idx];
  const float* wr = ada_w + idx * 512;
  for (int j = 0; j < 512; j++) acc += s_sc[j] * wr[j];
  mod[idx] = acc;
}

// ---------------- hn = LN(h)*(1+sc) + sm -> bf16 ----------------
__global__ __launch_bounds__(256) void st_ln(
    const float* __restrict__ h, const float* __restrict__ sm,
    const float* __restrict__ sc, unsigned short* __restrict__ hn) {
  int row = blockIdx.x * 4 + (threadIdx.x >> 6);
  int l = threadIdx.x & 63;
  const float4* hr = (const float4*)(h + (size_t)row * CDIM);
  float4 a = hr[l], b = hr[l + 64];
  float sum = a.x + a.y + a.z + a.w + b.x + b.y + b.z + b.w;
  float sq = a.x * a.x + a.y * a.y + a.z * a.z + a.w * a.w +
             b.x * b.x + b.y * b.y + b.z * b.z + b.w * b.w;
#pragma unroll
  for (int m = 1; m < 64; m <<= 1) {
    sum += __shfl_xor(sum, m, 64);
    sq += __shfl_xor(sq, m, 64);
  }
  float mean = sum * (1.0f / 512.0f);
  float var = sq * (1.0f / 512.0f) - mean * mean;
  float rs = rsqrtf(var + 1e-6f);
  const float4* sc4 = (const float4*)sc;
  const float4* sm4 = (const float4*)sm;
  float4 c0 = sc4[l], c1 = sc4[l + 64];
  float4 m0 = sm4[l], m1 = sm4[l + 64];
  ushort4 o0, o1;
  o0.x = f2bf((a.x - mean) * rs * (1.0f + c0.x) + m0.x);
  o0.y = f2bf((a.y - mean) * rs * (1.0f + c0.y) + m0.y);
  o0.z = f2bf((a.z - mean) * rs * (1.0f + c0.z) + m0.z);
  o0.w = f2bf((a.w - mean) * rs * (1.0f + c0.w) + m0.w);
  o1.x = f2bf((b.x - mean) * rs * (1.0f + c1.x) + m1.x);
  o1.y = f2bf((b.y - mean) * rs * (1.0f + c1.y) + m1.y);
  o1.z = f2bf((b.z - mean) * rs * (1.0f + c1.z) + m1.z);
  o1.w = f2bf((b.w - mean) * rs * (1.0f + c1.w) + m1.w);
  ushort4* out = (ushort4*)(hn + (size_t)row * CDIM);
  out[l] = o0;
  out[l + 64] = o1;
}

// ---------------- GEMM: C[M][Nout] = A[M][K]bf16 @ B[Nout][K]bf16^T ----------------
// EPI 0: +bias -> bf16 out (cols < qcols additionally scaled by 0.125*log2e —
//        folds the attention score scale into Q so st_attn skips the multiply)
// EPI 1: gelu(+bias) -> bf16 out
// EPI 2: h[row][col] += gate[col] * (acc + bias[col])   (fp32 residual)
template <int EPI>
__global__ __launch_bounds__(256, 2) void st_gemm(
    const unsigned short* __restrict__ A, const unsigned short* __restrict__ B,
    const float* __restrict__ bias, const float* __restrict__ gate,
    float* __restrict__ hbuf, unsigned short* __restrict__ outb,
    int K, int Nout, int qcols) {
  __shared__ __align__(16) unsigned short sA[128 * 64];
  __shared__ __align__(16) unsigned short sB[128 * 64];
  int tid = threadIdx.x;
  int wv = tid >> 6, l = tid & 63;
  int lr = l >> 3, lc = l & 7;
  int swz = (lc ^ lr) * 8;  // XOR swizzle (elems) baked into global read
  int bn = blockIdx.x, bm = blockIdx.y;
  const unsigned short* Ab = A + (size_t)bm * 128 * K;
  const unsigned short* Bb = B + (size_t)bn * 128 * K;
  int wm = (wv >> 1) * 64, wn = (wv & 1) * 64;
  int lanem = l & 15, quad = l >> 4;
  f32x4 acc[4][4] = {};
  for (int k0 = 0; k0 < K; k0 += 64) {
#pragma unroll
    for (int ii = 0; ii < 4; ii++) {
      int row = wv * 32 + ii * 8 + lr;
      async16(&sA[row * 64 + lc * 8], Ab + (size_t)row * K + k0 + swz);
      async16(&sB[row * 64 + lc * 8], Bb + (size_t)row * K + k0 + swz);
    }
    __syncthreads();
#pragma unroll
    for (int kk = 0; kk < 2; kk++) {
      int q = quad + kk * 4;
      bf16x8 af[4], bfr[4];
#pragma unroll
      for (int mi = 0; mi < 4; mi++) {
        int r = wm + mi * 16 + lanem;
        af[mi] = *(const bf16x8*)&sA[r * 64 + ((q ^ (r & 7)) * 8)];
      }
#pragma unroll
      for (int ni = 0; ni < 4; ni++) {
        int r = wn + ni * 16 + lanem;
        bfr[ni] = *(const bf16x8*)&sB[r * 64 + ((q ^ (r & 7)) * 8)];
      }
#pragma unroll
      for (int mi = 0; mi < 4; mi++)
#pragma unroll
        for (int ni = 0; ni < 4; ni++)
          acc[mi][ni] = __builtin_amdgcn_mfma_f32_16x16x32_bf16(af[mi], bfr[ni], acc[mi][ni], 0, 0, 0);
    }
    __syncthreads();
  }
#pragma unroll
  for (int mi = 0; mi < 4; mi++) {
#pragma unroll
    for (int ni = 0; ni < 4; ni++) {
      int col = bn * 128 + wn + ni * 16 + lanem;
      float bv = bias[col];
      float qscale = (EPI == 0 && col < qcols) ? 0.18033688f : 1.0f;
#pragma unroll
      for (int rg = 0; rg < 4; rg++) {
        int row = bm * 128 + wm + mi * 16 + quad * 4 + rg;
        float v = acc[mi][ni][rg] + bv;
        if (EPI == 0) {
          outb[(size_t)row * Nout + col] = f2bf(v * qscale);
        } else if (EPI == 1) {
          // tanh-approx gelu: x * sigmoid(2.3022082x + 0.10294326x^3), via exp2
          float arg = v * fmaf(0.10294326f, v * v, 2.3022082f);
          float g = v / (1.0f + exp2f(-arg));
          outb[(size_t)row * Nout + col] = f2bf(g);
        } else {
          size_t idx = (size_t)row * CDIM + col;
          hbuf[idx] = hbuf[idx] + gate[col] * v;
        }
      }
    }
  }
}

// ------- V transpose: vt[(w*8+h)*64+d][j] = f16(V[j][d]) (rolled window space) -------
__global__ __launch_bounds__(256) void st_vtrans(
    const unsigned short* __restrict__ qkv, unsigned short* __restrict__ vt, int shift) {
  __shared__ __align__(16) unsigned short tile[64][72];
  int jt = blockIdx.x, hh = blockIdx.y, wz = blockIdx.z;
  int t = threadIdx.x;
  int r = t >> 2, c0 = (t & 3) * 16;
  int g = (wz * 1024 + jt * 64 + r + shift) & NMASK;
  const uint4* src = (const uint4*)(qkv + (size_t)g * 1536 + 1024 + hh * 64 + c0);
  uint4 d0 = src[0], d1 = src[1];
  __align__(16) unsigned short vin[16];
  *(uint4*)&vin[0] = d0;
  *(uint4*)&vin[8] = d1;
#pragma unroll
  for (int jj = 0; jj < 16; jj++) {
    _Float16 hv = (_Float16)bf2f(vin[jj]);  // bf16 -> f16 (exact)
    tile[r][c0 + jj] = __builtin_bit_cast(unsigned short, hv);
  }
  __syncthreads();
  int d = t >> 2, j0 = (t & 3) * 16;
  __align__(16) unsigned short vals[16];
#pragma unroll
  for (int jj = 0; jj < 16; jj++) vals[jj] = tile[j0 + jj][d];
  unsigned short* dst = vt + ((size_t)(wz * 8 + hh) * 64 + d) * 1024 + jt * 64 + j0;
  *(uint4*)dst = *(uint4*)&vals[0];
  *(uint4*)(dst + 8) = *(uint4*)&vals[8];
}

// ---------------- window attention v3 ----------------
// Block = (qt, hh, wz): 128 Q rows, 4 waves x 32 rows; grid 1024 blocks ->
// 4 blocks/CU (16 waves/CU) at VGPR<=128, LDS 32KB.
// S^T = K·Q^T (Q pre-scaled by 0.125*log2e in the qkv GEMM epilogue) ->
// C-layout == B-operand layout of 16x16x16 f16 MFMA -> P packs in-register.
// Softmax denominator accumulated on the MFMA pipe via a ones-vector A-frag:
// every lane's C-frag then holds its column's rowsum (no adds, no shuffles).
__global__ __launch_bounds__(256, 4) void st_attn(
    const unsigned short* __restrict__ qkv, const unsigned short* __restrict__ vt,
    unsigned short* __restrict__ ao, int shift) {
  __shared__ __align__(16) unsigned short sK[2][64 * 64];
  __shared__ __align__(16) unsigned short sV[2][64 * 64];
  int qt = blockIdx.x, hh = blockIdx.y, wz = blockIdx.z;
  int tid = threadIdx.x;
  int wv = tid >> 6, l = tid & 63;
  int lanem = l & 15, quad = l >> 4;
  int wbase = wz * 1024;
  int qbase = wbase + qt * 128 + wv * 32;

  // Q fragments (B-operand layout for 16x16x32): lane n=i, k=d
  bf16x8 qf[2][2];
#pragma unroll
  for (int ni = 0; ni < 2; ni++) {
    int g = (qbase + ni * 16 + lanem + shift) & NMASK;
    const unsigned short* qp = qkv + (size_t)g * 1536 + hh * 64 + quad * 8;
    qf[ni][0] = *(const bf16x8*)qp;
    qf[ni][1] = *(const bf16x8*)(qp + 32);
  }
  const unsigned short* vbase = vt + (size_t)(wz * 8 + hh) * 64 * 1024;

  f32x4 oacc[4][2] = {};
  f32x4 osum[2] = {};
  f16x4 ones;
  ones[0] = (_Float16)1.0f; ones[1] = (_Float16)1.0f;
  ones[2] = (_Float16)1.0f; ones[3] = (_Float16)1.0f;

  // stage K-tile + V^T-tile kt into buffer b
  auto stage = [&](int b, int kt) {
#pragma unroll
    for (int ii = 0; ii < 2; ii++) {
      int chunk = ii * 256 + tid;
      int r = chunk >> 3, c = chunk & 7;
      int gk = (wbase + kt * 64 + r + shift) & NMASK;
      async16(&sK[b][chunk * 8], qkv + (size_t)gk * 1536 + 512 + hh * 64 + ((c ^ (r & 7)) * 8));
      async16(&sV[b][chunk * 8], vbase + (size_t)r * 1024 + kt * 64 + ((c ^ (r & 7)) * 8));
    }
  };

  stage(0, 0);
  int buf = 0;
  for (int kt = 0; kt < 16; kt++) {
    __syncthreads();  // drains staging vmcnt + protects buf^1 reuse
    if (kt < 15) stage(buf ^ 1, kt + 1);
    const unsigned short* Kb = &sK[buf][0];
    const unsigned short* Vb = &sV[buf][0];
#pragma unroll
    for (int mj = 0; mj < 4; mj++) {
      int r = mj * 16 + lanem;
      bf16x8 kf0 = *(const bf16x8*)&Kb[r * 64 + ((quad ^ (r & 7)) * 8)];
      bf16x8 kf1 = *(const bf16x8*)&Kb[r * 64 + (((4 + quad) ^ (r & 7)) * 8)];
      f16x4 vf[4];
#pragma unroll
      for (int dm = 0; dm < 4; dm++) {
        int d = dm * 16 + lanem;
        int phys = (((mj * 2 + (quad >> 1)) ^ (d & 7)) * 8) + (quad & 1) * 4;
        vf[dm] = *(const f16x4*)&Vb[d * 64 + phys];
      }
      f16x4 pf[2];
#pragma unroll
      for (int ni = 0; ni < 2; ni++) {
        f32x4 s = {};
        s = __builtin_amdgcn_mfma_f32_16x16x32_bf16(kf0, qf[ni][0], s, 0, 0, 0);
        s = __builtin_amdgcn_mfma_f32_16x16x32_bf16(kf1, qf[ni][1], s, 0, 0, 0);
        f16x2 lo = pk_f16(exp2f(s[0]), exp2f(s[1]));
        f16x2 hi = pk_f16(exp2f(s[2]), exp2f(s[3]));
        pf[ni] = __builtin_shufflevector(lo, hi, 0, 1, 2, 3);
        osum[ni] = __builtin_amdgcn_mfma_f32_16x16x16f16(ones, pf[ni], osum[ni], 0, 0, 0);
      }
#pragma unroll
      for (int dm = 0; dm < 4; dm++)
#pragma unroll
        for (int ni = 0; ni < 2; ni++)
          oacc[dm][ni] = __builtin_amdgcn_mfma_f32_16x16x16f16(vf[dm], pf[ni], oacc[dm][ni], 0, 0, 0);
    }
    buf ^= 1;
  }
#pragma unroll
  for (int ni = 0; ni < 2; ni++) {
    float inv = 1.0f / osum[ni][0];  // every C-row of the ones-MFMA == colsum
    int g = (qbase + ni * 16 + lanem + shift) & NMASK;
    unsigned short* orow = ao + (size_t)g * CDIM + hh * 64;
#pragma unroll
    for (int dm = 0; dm < 4; dm++) {
      ushort4 o;
      o.x = f2bf(oacc[dm][ni][0] * inv);
      o.y = f2bf(oacc[dm][ni][1] * inv);
      o.z = f2bf(oacc[dm][ni][2] * inv);
      o.w = f2bf(oacc[dm][ni][3] * inv);
      *(ushort4*)(orow + dm * 16 + quad * 4) = o;
    }
  }
}

// ---------------- out = h @ out_w^T + out_b (fp32) ----------------
__global__ __launch_bounds__(128) void st_outproj(
    const float* __restrict__ h, const float* __restrict__ out_w,
    const float* __restrict__ out_b, float* __restrict__ out) {
  __shared__ float sh[16 * 513];
  __shared__ float sw[8 * 520];
  int tid = threadIdx.x;
  int rbase = blockIdx.x * 16;
  for (int i = tid; i < 16 * 512; i += 128) {
    int r = i >> 9, c = i & 511;
    sh[r * 513 + c] = h[(size_t)(rbase + r) * 512 + c];
  }
  for (int i = tid; i < 8 * 512; i += 128) {
    int r = i >> 9, c = i & 511;
    sw[r * 520 + c] = out_w[i];
  }
  __syncthreads();
  int r = tid >> 3, co = tid & 7;
  float acc = out_b[co];
  const float* hr = sh + r * 513;
  const float* wr = sw + co * 520;
  for (int c = 0; c < 512; c++) acc += hr[c] * wr[c];
  out[(size_t)(rbase + r) * 8 + co] = acc;
}

extern "C" void kernel_launch(void* const* d_in, const int* in_sizes, int n_in,
                              void* d_out, int out_size, void* d_ws, size_t ws_size,
                              hipStream_t stream) {
  const float* feats = (const float*)d_in[0];
  const int* coords = (const int*)d_in[1];
  const float* tptr = (const float*)d_in[2];
  const float* in_w = (const float*)d_in[3];
  const float* in_b = (const float*)d_in[4];
  const float* t_w1 = (const float*)d_in[5];
  const float* t_b1 = (const float*)d_in[6];
  const float* t_w2 = (const float*)d_in[7];
  const float* t_b2 = (const float*)d_in[8];
  const float* qkv_w = (const float*)d_in[9];
  const float* qkv_b = (const float*)d_in[10];
  const float* proj_w = (const float*)d_in[11];
  const float* proj_b = (const float*)d_in[12];
  const float* ada_w = (const float*)d_in[13];
  const float* ada_b = (const float*)d_in[14];
  const float* fc1_w = (const float*)d_in[15];
  const float* fc1_b = (const float*)d_in[16];
  const float* fc2_w = (const float*)d_in[17];
  const float* fc2_b = (const float*)d_in[18];
  const float* out_w = (const float*)d_in[19];
  const float* out_b = (const float*)d_in[20];
  float* out = (float*)d_out;

  char* ws = (char*)d_ws;
  size_t off = 0;
  auto alloc = [&](size_t bytes) {
    char* p = ws + off;
    off += (bytes + 255) & ~(size_t)255;
    return p;
  };
  unsigned short* w_qkv = (unsigned short*)alloc((size_t)8 * 1536 * 512 * 2);
  unsigned short* w_proj = (unsigned short*)alloc((size_t)8 * 512 * 512 * 2);
  unsigned short* w_fc1 = (unsigned short*)alloc((size_t)8 * 2048 * 512 * 2);
  unsigned short* w_fc2 = (unsigned short*)alloc((size_t)8 * 512 * 2048 * 2);
  float* h = (float*)alloc((size_t)NTOK * 512 * 4);
  unsigned short* hn = (unsigned short*)alloc((size_t)NTOK * 512 * 2);
  unsigned short* big = (unsigned short*)alloc((size_t)NTOK * 2048 * 2);  // qkv, then ffn-mid
  unsigned short* ao = (unsigned short*)alloc((size_t)NTOK * 512 * 2);
  unsigned short* vtb = (unsigned short*)alloc((size_t)16 * 8 * 64 * 1024 * 2);
  float* cbuf = (float*)alloc(512 * 4);
  float* mod = (float*)alloc((size_t)8 * 3072 * 4);
  if (ws_size < off) return;  // insufficient workspace -> fail loudly at validation

  st_cvt_bf16<<<512, 256, 0, stream>>>((const float4*)qkv_w, (ushort4*)w_qkv, 8 * 1536 * 512 / 4);
  st_cvt_bf16<<<512, 256, 0, stream>>>((const float4*)proj_w, (ushort4*)w_proj, 8 * 512 * 512 / 4);
  st_cvt_bf16<<<512, 256, 0, stream>>>((const float4*)fc1_w, (ushort4*)w_fc1, 8 * 2048 * 512 / 4);
  st_cvt_bf16<<<512, 256, 0, stream>>>((const float4*)fc2_w, (ushort4*)w_fc2, 8 * 512 * 2048 / 4);
  st_embed<<<NTOK, 512, 0, stream>>>(feats, coords, in_w, in_b, h);
  st_tembed1<<<1, 512, 0, stream>>>(tptr, t_w1, t_b1, t_w2, t_b2, cbuf);
  st_tembed2<<<96, 256, 0, stream>>>(cbuf, ada_w, ada_b, mod);

  for (int i = 0; i < 8; i++) {
    int shift = (i & 1) ? 512 : 0;
    const float* modl = mod + i * 3072;
    // attn branch
    st_ln<<<4096, 256, 0, stream>>>(h, modl, modl + 512, hn);
    st_gemm<0><<<dim3(12, 128), 256, 0, stream>>>(hn, w_qkv + (size_t)i * 1536 * 512,
                                                  qkv_b + i * 1536, nullptr, nullptr, big, 512, 1536, 512);
    st_vtrans<<<dim3(16, 8, 16), 256, 0, stream>>>(big, vtb, shift);
    st_attn<<<dim3(8, 8, 16), 256, 0, stream>>>(big, vtb, ao, shift);
    st_gemm<2><<<dim3(4, 128), 256, 0, stream>>>(ao, w_proj + (size_t)i * 512 * 512,
                                                 proj_b + i * 512, modl + 1024, h, nullptr, 512, 512, 0);
    // mlp branch
    st_ln<<<4096, 256, 0, stream>>>(h, modl + 1536, modl + 2048, hn);
    st_gemm<1><<<dim3(16, 128), 256, 0, stream>>>(hn, w_fc1 + (size_t)i * 2048 * 512,
                                                  fc1_b + i * 2048, nullptr, nullptr, big, 512, 2048, 0);
    st_gemm<2><<<dim3(4, 128), 256, 0, stream>>>(big, w_fc2 + (size_t)i * 512 * 2048,
                                                 fc2_b + i * 512, modl + 2560, h, nullptr, 2048, 512, 0);
  }
  st_outproj<<<1024, 128, 0, stream>>>(h, out_w, out_b, out);
}

// Round 5
// 2324.210 us; speedup vs baseline: 1.0417x; 1.0417x over previous
//
#include <hip/hip_runtime.h>
#include <cstdint>
#include <cstddef>

typedef __bf16 bf16x8 __attribute__((ext_vector_type(8)));
typedef _Float16 f16x4 __attribute__((ext_vector_type(4)));
typedef _Float16 f16x2 __attribute__((ext_vector_type(2)));
typedef float f32x4 __attribute__((ext_vector_type(4)));

#define NTOK 16384
#define NMASK 16383
#define CDIM 512

__device__ __forceinline__ unsigned short f2bf(float f) {
  __bf16 b = (__bf16)f;
  return __builtin_bit_cast(unsigned short, b);
}
__device__ __forceinline__ float bf2f(unsigned short u) {
  return __builtin_bit_cast(float, (unsigned int)u << 16);
}
__device__ __forceinline__ f16x2 pk_f16(float a, float b) {
  return __builtin_bit_cast(f16x2, __builtin_amdgcn_cvt_pkrtz(a, b));
}

// async 16B global -> LDS (wave-uniform base + lane*16 semantics)
__device__ __forceinline__ void async16(unsigned short* lds, const unsigned short* g) {
  __builtin_amdgcn_global_load_lds(
      (__attribute__((address_space(1))) void*)(g),
      (__attribute__((address_space(3))) void*)(lds), 16, 0, 0);
}

// ---------------- fp32 -> bf16 conversion (weights) ----------------
__global__ void st_cvt_bf16(const float4* __restrict__ src, ushort4* __restrict__ dst, int n4) {
  int i = blockIdx.x * blockDim.x + threadIdx.x;
  int stride = gridDim.x * blockDim.x;
  for (; i < n4; i += stride) {
    float4 f = src[i];
    ushort4 o;
    o.x = f2bf(f.x); o.y = f2bf(f.y); o.z = f2bf(f.z); o.w = f2bf(f.w);
    dst[i] = o;
  }
}

// ---------------- h = feats @ in_w^T + in_b + pos_embed ----------------
__global__ __launch_bounds__(512) void st_embed(
    const float* __restrict__ feats, const int* __restrict__ coords,
    const float* __restrict__ in_w, const float* __restrict__ in_b,
    float* __restrict__ h) {
  int n = blockIdx.x;
  int c = threadIdx.x;
  float acc = in_b[c];
  const float* fr = feats + n * 8;
  const float* wr = in_w + c * 8;
#pragma unroll
  for (int k = 0; k < 8; k++) acc += fr[k] * wr[k];
  if (c < 510) {
    int g = c / 170;
    int cc = c - g * 170;
    int j = (cc < 85) ? cc : (cc - 85);
    float freq = exp2f(-0.15632603f * (float)j);  // 1/10000^(j/85)
    float o = (float)coords[n * 3 + g] * freq;
    acc += (cc < 85) ? sinf(o) : cosf(o);
  }
  h[(size_t)n * CDIM + c] = acc;
}

// ---------------- t-embedding -> c vector (512) ----------------
__global__ __launch_bounds__(512) void st_tembed1(
    const float* __restrict__ tptr,
    const float* __restrict__ w1, const float* __restrict__ b1,
    const float* __restrict__ w2, const float* __restrict__ b2,
    float* __restrict__ cbuf) {
  __shared__ float s_emb[256];
  __shared__ float s_h[512];
  int tid = threadIdx.x;
  float t = tptr[0];
  if (tid < 256) {
    int j = tid & 127;
    float fr = exp2f(-0.10381025f * (float)j);  // exp(-ln(1e4)*j/128)
    float a = t * fr;
    s_emb[tid] = (tid < 128) ? cosf(a) : sinf(a);
  }
  __syncthreads();
  float acc = b1[tid];
  const float* w1r = w1 + (size_t)tid * 256;
  for (int j = 0; j < 256; j++) acc += s_emb[j] * w1r[j];
  s_h[tid] = acc / (1.0f + exp2f(-1.44269504f * acc));  // silu
  __syncthreads();
  float acc2 = b2[tid];
  const float* w2r = w2 + (size_t)tid * 512;
  for (int j = 0; j < 512; j++) acc2 += s_h[j] * w2r[j];
  cbuf[tid] = acc2;
}

// ---------------- mod[l] = silu(c) @ ada_w[l]^T + ada_b[l] ----------------
__global__ __launch_bounds__(256) void st_tembed2(
    const float* __restrict__ cbuf, const float* __restrict__ ada_w,
    const float* __restrict__ ada_b, float* __restrict__ mod) {
  __shared__ float s_sc[512];
  int tid = threadIdx.x;
  for (int i = tid; i < 512; i += 256) {
    float v = cbuf[i];
    s_sc[i] = v / (1.0f + exp2f(-1.44269504f * v));
  }
  __syncthreads();
  int l = blockIdx.x / 12;
  int o = (blockIdx.x % 12) * 256 + tid;
  size_t idx = (size_t)l * 3072 + o;
  float acc = ada_b[idx];
  const float* wr = ada_w + idx * 512;
  for (int j = 0; j < 512; j++) acc += s_sc[j] * wr[j];
  mod[idx] = acc;
}

// ---------------- hn = LN(h)*(1+sc) + sm -> bf16 ----------------
__global__ __launch_bounds__(256) void st_ln(
    const float* __restrict__ h, const float* __restrict__ sm,
    const float* __restrict__ sc, unsigned short* __restrict__ hn) {
  int row = blockIdx.x * 4 + (threadIdx.x >> 6);
  int l = threadIdx.x & 63;
  const float4* hr = (const float4*)(h + (size_t)row * CDIM);
  float4 a = hr[l], b = hr[l + 64];
  float sum = a.x + a.y + a.z + a.w + b.x + b.y + b.z + b.w;
  float sq = a.x * a.x + a.y * a.y + a.z * a.z + a.w * a.w +
             b.x * b.x + b.y * b.y + b.z * b.z + b.w * b.w;
#pragma unroll
  for (int m = 1; m < 64; m <<= 1) {
    sum += __shfl_xor(sum, m, 64);
    sq += __shfl_xor(sq, m, 64);
  }
  float mean = sum * (1.0f / 512.0f);
  float var = sq * (1.0f / 512.0f) - mean * mean;
  float rs = rsqrtf(var + 1e-6f);
  const float4* sc4 = (const float4*)sc;
  const float4* sm4 = (const float4*)sm;
  float4 c0 = sc4[l], c1 = sc4[l + 64];
  float4 m0 = sm4[l], m1 = sm4[l + 64];
  ushort4 o0, o1;
  o0.x = f2bf((a.x - mean) * rs * (1.0f + c0.x) + m0.x);
  o0.y = f2bf((a.y - mean) * rs * (1.0f + c0.y) + m0.y);
  o0.z = f2bf((a.z - mean) * rs * (1.0f + c0.z) + m0.z);
  o0.w = f2bf((a.w - mean) * rs * (1.0f + c0.w) + m0.w);
  o1.x = f2bf((b.x - mean) * rs * (1.0f + c1.x) + m1.x);
  o1.y = f2bf((b.y - mean) * rs * (1.0f + c1.y) + m1.y);
  o1.z = f2bf((b.z - mean) * rs * (1.0f + c1.z) + m1.z);
  o1.w = f2bf((b.w - mean) * rs * (1.0f + c1.w) + m1.w);
  ushort4* out = (ushort4*)(hn + (size_t)row * CDIM);
  out[l] = o0;
  out[l + 64] = o1;
}

// ---------------- GEMM: C[M][Nout] = A[M][K]bf16 @ B[Nout][K]bf16^T ----------------
// 1D grid, id = bn*128 + bm  ->  all bn-tiles of one A row-block share an XCD
// (XCD = bm & 7) so A is fetched into that XCD's L2 once.
// EPI 0: +bias -> bf16 out (cols < qcols additionally scaled by 0.125*log2e)
// EPI 1: gelu(+bias) -> bf16 out
// EPI 2: h[row][col] += gate[col] * (acc + bias[col])   (fp32 residual)
template <int EPI>
__global__ __launch_bounds__(256, 2) void st_gemm(
    const unsigned short* __restrict__ A, const unsigned short* __restrict__ B,
    const float* __restrict__ bias, const float* __restrict__ gate,
    float* __restrict__ hbuf, unsigned short* __restrict__ outb,
    int K, int Nout, int qcols) {
  __shared__ __align__(16) unsigned short sA[128 * 64];
  __shared__ __align__(16) unsigned short sB[128 * 64];
  int tid = threadIdx.x;
  int wv = tid >> 6, l = tid & 63;
  int lr = l >> 3, lc = l & 7;
  int swz = (lc ^ lr) * 8;  // XOR swizzle (elems) baked into global read
  int bn = blockIdx.x >> 7, bm = blockIdx.x & 127;
  const unsigned short* Ab = A + (size_t)bm * 128 * K;
  const unsigned short* Bb = B + (size_t)bn * 128 * K;
  int wm = (wv >> 1) * 64, wn = (wv & 1) * 64;
  int lanem = l & 15, quad = l >> 4;
  f32x4 acc[4][4] = {};
  for (int k0 = 0; k0 < K; k0 += 64) {
#pragma unroll
    for (int ii = 0; ii < 4; ii++) {
      int row = wv * 32 + ii * 8 + lr;
      async16(&sA[row * 64 + lc * 8], Ab + (size_t)row * K + k0 + swz);
      async16(&sB[row * 64 + lc * 8], Bb + (size_t)row * K + k0 + swz);
    }
    __syncthreads();
#pragma unroll
    for (int kk = 0; kk < 2; kk++) {
      int q = quad + kk * 4;
      bf16x8 af[4], bfr[4];
#pragma unroll
      for (int mi = 0; mi < 4; mi++) {
        int r = wm + mi * 16 + lanem;
        af[mi] = *(const bf16x8*)&sA[r * 64 + ((q ^ (r & 7)) * 8)];
      }
#pragma unroll
      for (int ni = 0; ni < 4; ni++) {
        int r = wn + ni * 16 + lanem;
        bfr[ni] = *(const bf16x8*)&sB[r * 64 + ((q ^ (r & 7)) * 8)];
      }
#pragma unroll
      for (int mi = 0; mi < 4; mi++)
#pragma unroll
        for (int ni = 0; ni < 4; ni++)
          acc[mi][ni] = __builtin_amdgcn_mfma_f32_16x16x32_bf16(af[mi], bfr[ni], acc[mi][ni], 0, 0, 0);
    }
    __syncthreads();
  }
#pragma unroll
  for (int mi = 0; mi < 4; mi++) {
#pragma unroll
    for (int ni = 0; ni < 4; ni++) {
      int col = bn * 128 + wn + ni * 16 + lanem;
      float bv = bias[col];
      float qscale = (EPI == 0 && col < qcols) ? 0.18033688f : 1.0f;
#pragma unroll
      for (int rg = 0; rg < 4; rg++) {
        int row = bm * 128 + wm + mi * 16 + quad * 4 + rg;
        float v = acc[mi][ni][rg] + bv;
        if (EPI == 0) {
          outb[(size_t)row * Nout + col] = f2bf(v * qscale);
        } else if (EPI == 1) {
          // tanh-approx gelu: x * sigmoid(2.3022082x + 0.10294326x^3), via exp2
          float arg = v * fmaf(0.10294326f, v * v, 2.3022082f);
          float g = v / (1.0f + exp2f(-arg));
          outb[(size_t)row * Nout + col] = f2bf(g);
        } else {
          size_t idx = (size_t)row * CDIM + col;
          hbuf[idx] = hbuf[idx] + gate[col] * v;
        }
      }
    }
  }
}

// ------- V transpose: vt[(w*8+h)*64+d][j] = f16(V[j][d]) (rolled window space) -------
// 1D grid, id = jt*128 + hh*16 + wz  ->  XCD = wz & 7 (matches st_attn consumer)
__global__ __launch_bounds__(256) void st_vtrans(
    const unsigned short* __restrict__ qkv, unsigned short* __restrict__ vt, int shift) {
  __shared__ __align__(16) unsigned short tile[64][72];
  int id = blockIdx.x;
  int jt = id >> 7, hh = (id >> 4) & 7, wz = id & 15;
  int t = threadIdx.x;
  int r = t >> 2, c0 = (t & 3) * 16;
  int g = (wz * 1024 + jt * 64 + r + shift) & NMASK;
  const uint4* src = (const uint4*)(qkv + (size_t)g * 1536 + 1024 + hh * 64 + c0);
  uint4 d0 = src[0], d1 = src[1];
  __align__(16) unsigned short vin[16];
  *(uint4*)&vin[0] = d0;
  *(uint4*)&vin[8] = d1;
#pragma unroll
  for (int jj = 0; jj < 16; jj++) {
    _Float16 hv = (_Float16)bf2f(vin[jj]);  // bf16 -> f16 (exact)
    tile[r][c0 + jj] = __builtin_bit_cast(unsigned short, hv);
  }
  __syncthreads();
  int d = t >> 2, j0 = (t & 3) * 16;
  __align__(16) unsigned short vals[16];
#pragma unroll
  for (int jj = 0; jj < 16; jj++) vals[jj] = tile[j0 + jj][d];
  unsigned short* dst = vt + ((size_t)(wz * 8 + hh) * 64 + d) * 1024 + jt * 64 + j0;
  *(uint4*)dst = *(uint4*)&vals[0];
  *(uint4*)(dst + 8) = *(uint4*)&vals[8];
}

// ---------------- window attention v4 ----------------
// 1D grid 1024, id = qt*128 + hh*16 + wz  ->  XCD = wz & 7: all 8 qt-blocks of
// one (window,head) land on the same XCD so K/V is fetched into its L2 once.
// S^T = K·Q^T (Q pre-scaled by 0.125*log2e in the qkv GEMM epilogue) ->
// C-layout == B-operand layout of 16x16x16 f16 MFMA -> P packs in-register.
// Softmax denominator accumulated on the MFMA pipe via a ones-vector A-frag.
__global__ __launch_bounds__(256, 4) void st_attn(
    const unsigned short* __restrict__ qkv, const unsigned short* __restrict__ vt,
    unsigned short* __restrict__ ao, int shift) {
  __shared__ __align__(16) unsigned short sK[2][64 * 64];
  __shared__ __align__(16) unsigned short sV[2][64 * 64];
  int id = blockIdx.x;
  int qt = id >> 7, hh = (id >> 4) & 7, wz = id & 15;
  int tid = threadIdx.x;
  int wv = tid >> 6, l = tid & 63;
  int lanem = l & 15, quad = l >> 4;
  int wbase = wz * 1024;
  int qbase = wbase + qt * 128 + wv * 32;

  // Q fragments (B-operand layout for 16x16x32): lane n=i, k=d
  bf16x8 qf[2][2];
#pragma unroll
  for (int ni = 0; ni < 2; ni++) {
    int g = (qbase + ni * 16 + lanem + shift) & NMASK;
    const unsigned short* qp = qkv + (size_t)g * 1536 + hh * 64 + quad * 8;
    qf[ni][0] = *(const bf16x8*)qp;
    qf[ni][1] = *(const bf16x8*)(qp + 32);
  }
  const unsigned short* vbase = vt + (size_t)(wz * 8 + hh) * 64 * 1024;

  f32x4 oacc[4][2] = {};
  f32x4 osum[2] = {};
  f16x4 ones;
  ones[0] = (_Float16)1.0f; ones[1] = (_Float16)1.0f;
  ones[2] = (_Float16)1.0f; ones[3] = (_Float16)1.0f;

  // stage K-tile + V^T-tile kt into buffer b
  auto stage = [&](int b, int kt) {
#pragma unroll
    for (int ii = 0; ii < 2; ii++) {
      int chunk = ii * 256 + tid;
      int r = chunk >> 3, c = chunk & 7;
      int gk = (wbase + kt * 64 + r + shift) & NMASK;
      async16(&sK[b][chunk * 8], qkv + (size_t)gk * 1536 + 512 + hh * 64 + ((c ^ (r & 7)) * 8));
      async16(&sV[b][chunk * 8], vbase + (size_t)r * 1024 + kt * 64 + ((c ^ (r & 7)) * 8));
    }
  };

  stage(0, 0);
  int buf = 0;
  for (int kt = 0; kt < 16; kt++) {
    __syncthreads();  // drains staging vmcnt + protects buf^1 reuse
    if (kt < 15) stage(buf ^ 1, kt + 1);
    const unsigned short* Kb = &sK[buf][0];
    const unsigned short* Vb = &sV[buf][0];
#pragma unroll
    for (int mj = 0; mj < 4; mj++) {
      int r = mj * 16 + lanem;
      bf16x8 kf0 = *(const bf16x8*)&Kb[r * 64 + ((quad ^ (r & 7)) * 8)];
      bf16x8 kf1 = *(const bf16x8*)&Kb[r * 64 + (((4 + quad) ^ (r & 7)) * 8)];
      f16x4 vf[4];
#pragma unroll
      for (int dm = 0; dm < 4; dm++) {
        int d = dm * 16 + lanem;
        int phys = (((mj * 2 + (quad >> 1)) ^ (d & 7)) * 8) + (quad & 1) * 4;
        vf[dm] = *(const f16x4*)&Vb[d * 64 + phys];
      }
      f16x4 pf[2];
#pragma unroll
      for (int ni = 0; ni < 2; ni++) {
        f32x4 s = {};
        s = __builtin_amdgcn_mfma_f32_16x16x32_bf16(kf0, qf[ni][0], s, 0, 0, 0);
        s = __builtin_amdgcn_mfma_f32_16x16x32_bf16(kf1, qf[ni][1], s, 0, 0, 0);
        f16x2 lo = pk_f16(exp2f(s[0]), exp2f(s[1]));
        f16x2 hi = pk_f16(exp2f(s[2]), exp2f(s[3]));
        pf[ni] = __builtin_shufflevector(lo, hi, 0, 1, 2, 3);
        osum[ni] = __builtin_amdgcn_mfma_f32_16x16x16f16(ones, pf[ni], osum[ni], 0, 0, 0);
      }
#pragma unroll
      for (int dm = 0; dm < 4; dm++)
#pragma unroll
        for (int ni = 0; ni < 2; ni++)
          oacc[dm][ni] = __builtin_amdgcn_mfma_f32_16x16x16f16(vf[dm], pf[ni], oacc[dm][ni], 0, 0, 0);
    }
    buf ^= 1;
  }
#pragma unroll
  for (int ni = 0; ni < 2; ni++) {
    float inv = 1.0f / osum[ni][0];  // every C-row of the ones-MFMA == colsum
    int g = (qbase + ni * 16 + lanem + shift) & NMASK;
    unsigned short* orow = ao + (size_t)g * CDIM + hh * 64;
#pragma unroll
    for (int dm = 0; dm < 4; dm++) {
      ushort4 o;
      o.x = f2bf(oacc[dm][ni][0] * inv);
      o.y = f2bf(oacc[dm][ni][1] * inv);
      o.z = f2bf(oacc[dm][ni][2] * inv);
      o.w = f2bf(oacc[dm][ni][3] * inv);
      *(ushort4*)(orow + dm * 16 + quad * 4) = o;
    }
  }
}

// ---------------- out = h @ out_w^T + out_b (fp32) ----------------
__global__ __launch_bounds__(128) void st_outproj(
    const float* __restrict__ h, const float* __restrict__ out_w,
    const float* __restrict__ out_b, float* __restrict__ out) {
  __shared__ float sh[16 * 513];
  __shared__ float sw[8 * 520];
  int tid = threadIdx.x;
  int rbase = blockIdx.x * 16;
  for (int i = tid; i < 16 * 512; i += 128) {
    int r = i >> 9, c = i & 511;
    sh[r * 513 + c] = h[(size_t)(rbase + r) * 512 + c];
  }
  for (int i = tid; i < 8 * 512; i += 128) {
    int r = i >> 9, c = i & 511;
    sw[r * 520 + c] = out_w[i];
  }
  __syncthreads();
  int r = tid >> 3, co = tid & 7;
  float acc = out_b[co];
  const float* hr = sh + r * 513;
  const float* wr = sw + co * 520;
  for (int c = 0; c < 512; c++) acc += hr[c] * wr[c];
  out[(size_t)(rbase + r) * 8 + co] = acc;
}

extern "C" void kernel_launch(void* const* d_in, const int* in_sizes, int n_in,
                              void* d_out, int out_size, void* d_ws, size_t ws_size,
                              hipStream_t stream) {
  const float* feats = (const float*)d_in[0];
  const int* coords = (const int*)d_in[1];
  const float* tptr = (const float*)d_in[2];
  const float* in_w = (const float*)d_in[3];
  const float* in_b = (const float*)d_in[4];
  const float* t_w1 = (const float*)d_in[5];
  const float* t_b1 = (const float*)d_in[6];
  const float* t_w2 = (const float*)d_in[7];
  const float* t_b2 = (const float*)d_in[8];
  const float* qkv_w = (const float*)d_in[9];
  const float* qkv_b = (const float*)d_in[10];
  const float* proj_w = (const float*)d_in[11];
  const float* proj_b = (const float*)d_in[12];
  const float* ada_w = (const float*)d_in[13];
  const float* ada_b = (const float*)d_in[14];
  const float* fc1_w = (const float*)d_in[15];
  const float* fc1_b = (const float*)d_in[16];
  const float* fc2_w = (const float*)d_in[17];
  const float* fc2_b = (const float*)d_in[18];
  const float* out_w = (const float*)d_in[19];
  const float* out_b = (const float*)d_in[20];
  float* out = (float*)d_out;

  char* ws = (char*)d_ws;
  size_t off = 0;
  auto alloc = [&](size_t bytes) {
    char* p = ws + off;
    off += (bytes + 255) & ~(size_t)255;
    return p;
  };
  unsigned short* w_qkv = (unsigned short*)alloc((size_t)8 * 1536 * 512 * 2);
  unsigned short* w_proj = (unsigned short*)alloc((size_t)8 * 512 * 512 * 2);
  unsigned short* w_fc1 = (unsigned short*)alloc((size_t)8 * 2048 * 512 * 2);
  unsigned short* w_fc2 = (unsigned short*)alloc((size_t)8 * 512 * 2048 * 2);
  float* h = (float*)alloc((size_t)NTOK * 512 * 4);
  unsigned short* hn = (unsigned short*)alloc((size_t)NTOK * 512 * 2);
  unsigned short* big = (unsigned short*)alloc((size_t)NTOK * 2048 * 2);  // qkv, then ffn-mid
  unsigned short* ao = (unsigned short*)alloc((size_t)NTOK * 512 * 2);
  unsigned short* vtb = (unsigned short*)alloc((size_t)16 * 8 * 64 * 1024 * 2);
  float* cbuf = (float*)alloc(512 * 4);
  float* mod = (float*)alloc((size_t)8 * 3072 * 4);
  if (ws_size < off) return;  // insufficient workspace -> fail loudly at validation

  st_cvt_bf16<<<512, 256, 0, stream>>>((const float4*)qkv_w, (ushort4*)w_qkv, 8 * 1536 * 512 / 4);
  st_cvt_bf16<<<512, 256, 0, stream>>>((const float4*)proj_w, (ushort4*)w_proj, 8 * 512 * 512 / 4);
  st_cvt_bf16<<<512, 256, 0, stream>>>((const float4*)fc1_w, (ushort4*)w_fc1, 8 * 2048 * 512 / 4);
  st_cvt_bf16<<<512, 256, 0, stream>>>((const float4*)fc2_w, (ushort4*)w_fc2, 8 * 512 * 2048 / 4);
  st_embed<<<NTOK, 512, 0, stream>>>(feats, coords, in_w, in_b, h);
  st_tembed1<<<1, 512, 0, stream>>>(tptr, t_w1, t_b1, t_w2, t_b2, cbuf);
  st_tembed2<<<96, 256, 0, stream>>>(cbuf, ada_w, ada_b, mod);

  for (int i = 0; i < 8; i++) {
    int shift = (i & 1) ? 512 : 0;
    const float* modl = mod + i * 3072;
    // attn branch
    st_ln<<<4096, 256, 0, stream>>>(h, modl, modl + 512, hn);
    st_gemm<0><<<12 * 128, 256, 0, stream>>>(hn, w_qkv + (size_t)i * 1536 * 512,
                                             qkv_b + i * 1536, nullptr, nullptr, big, 512, 1536, 512);
    st_vtrans<<<16 * 128, 256, 0, stream>>>(big, vtb, shift);
    st_attn<<<8 * 128, 256, 0, stream>>>(big, vtb, ao, shift);
    st_gemm<2><<<4 * 128, 256, 0, stream>>>(ao, w_proj + (size_t)i * 512 * 512,
                                            proj_b + i * 512, modl + 1024, h, nullptr, 512, 512, 0);
    // mlp branch
    st_ln<<<4096, 256, 0, stream>>>(h, modl + 1536, modl + 2048, hn);
    st_gemm<1><<<16 * 128, 256, 0, stream>>>(hn, w_fc1 + (size_t)i * 2048 * 512,
                                             fc1_b + i * 2048, nullptr, nullptr, big, 512, 2048, 0);
    st_gemm<2><<<4 * 128, 256, 0, stream>>>(big, w_fc2 + (size_t)i * 512 * 2048,
                                            fc2_b + i * 512, modl + 2560, h, nullptr, 2048, 512, 0);
  }
  st_outproj<<<1024, 128, 0, stream>>>(h, out_w, out_b, out);
}

// Round 6
// 2279.001 us; speedup vs baseline: 1.0623x; 1.0198x over previous
//
#include <hip/hip_runtime.h>
#include <cstdint>
#include <cstddef>

typedef __bf16 bf16x8 __attribute__((ext_vector_type(8)));
typedef _Float16 f16x4 __attribute__((ext_vector_type(4)));
typedef _Float16 f16x2 __attribute__((ext_vector_type(2)));
typedef float f32x4 __attribute__((ext_vector_type(4)));

#define NTOK 16384
#define NMASK 16383
#define CDIM 512

__device__ __forceinline__ unsigned short f2bf(float f) {
  __bf16 b = (__bf16)f;
  return __builtin_bit_cast(unsigned short, b);
}
__device__ __forceinline__ float bf2f(unsigned short u) {
  return __builtin_bit_cast(float, (unsigned int)u << 16);
}
__device__ __forceinline__ f16x2 pk_f16(float a, float b) {
  return __builtin_bit_cast(f16x2, __builtin_amdgcn_cvt_pkrtz(a, b));
}

// async 16B global -> LDS (wave-uniform base + lane*16 semantics)
__device__ __forceinline__ void async16(unsigned short* lds, const unsigned short* g) {
  __builtin_amdgcn_global_load_lds(
      (__attribute__((address_space(1))) void*)(g),
      (__attribute__((address_space(3))) void*)(lds), 16, 0, 0);
}

// ---------------- fp32 -> bf16 conversion (weights) ----------------
__global__ void st_cvt_bf16(const float4* __restrict__ src, ushort4* __restrict__ dst, int n4) {
  int i = blockIdx.x * blockDim.x + threadIdx.x;
  int stride = gridDim.x * blockDim.x;
  for (; i < n4; i += stride) {
    float4 f = src[i];
    ushort4 o;
    o.x = f2bf(f.x); o.y = f2bf(f.y); o.z = f2bf(f.z); o.w = f2bf(f.w);
    dst[i] = o;
  }
}

// ---------------- h = feats @ in_w^T + in_b + pos_embed ----------------
__global__ __launch_bounds__(512) void st_embed(
    const float* __restrict__ feats, const int* __restrict__ coords,
    const float* __restrict__ in_w, const float* __restrict__ in_b,
    float* __restrict__ h) {
  int n = blockIdx.x;
  int c = threadIdx.x;
  float acc = in_b[c];
  const float* fr = feats + n * 8;
  const float* wr = in_w + c * 8;
#pragma unroll
  for (int k = 0; k < 8; k++) acc += fr[k] * wr[k];
  if (c < 510) {
    int g = c / 170;
    int cc = c - g * 170;
    int j = (cc < 85) ? cc : (cc - 85);
    float freq = exp2f(-0.15632603f * (float)j);  // 1/10000^(j/85)
    float o = (float)coords[n * 3 + g] * freq;
    acc += (cc < 85) ? sinf(o) : cosf(o);
  }
  h[(size_t)n * CDIM + c] = acc;
}

// ---------------- t-embedding -> c vector (512) ----------------
__global__ __launch_bounds__(512) void st_tembed1(
    const float* __restrict__ tptr,
    const float* __restrict__ w1, const float* __restrict__ b1,
    const float* __restrict__ w2, const float* __restrict__ b2,
    float* __restrict__ cbuf) {
  __shared__ float s_emb[256];
  __shared__ float s_h[512];
  int tid = threadIdx.x;
  float t = tptr[0];
  if (tid < 256) {
    int j = tid & 127;
    float fr = exp2f(-0.10381025f * (float)j);  // exp(-ln(1e4)*j/128)
    float a = t * fr;
    s_emb[tid] = (tid < 128) ? cosf(a) : sinf(a);
  }
  __syncthreads();
  float acc = b1[tid];
  const float* w1r = w1 + (size_t)tid * 256;
  for (int j = 0; j < 256; j++) acc += s_emb[j] * w1r[j];
  s_h[tid] = acc / (1.0f + exp2f(-1.44269504f * acc));  // silu
  __syncthreads();
  float acc2 = b2[tid];
  const float* w2r = w2 + (size_t)tid * 512;
  for (int j = 0; j < 512; j++) acc2 += s_h[j] * w2r[j];
  cbuf[tid] = acc2;
}

// ---------------- mod[l] = silu(c) @ ada_w[l]^T + ada_b[l] ----------------
__global__ __launch_bounds__(256) void st_tembed2(
    const float* __restrict__ cbuf, const float* __restrict__ ada_w,
    const float* __restrict__ ada_b, float* __restrict__ mod) {
  __shared__ float s_sc[512];
  int tid = threadIdx.x;
  for (int i = tid; i < 512; i += 256) {
    float v = cbuf[i];
    s_sc[i] = v / (1.0f + exp2f(-1.44269504f * v));
  }
  __syncthreads();
  int l = blockIdx.x / 12;
  int o = (blockIdx.x % 12) * 256 + tid;
  size_t idx = (size_t)l * 3072 + o;
  float acc = ada_b[idx];
  const float* wr = ada_w + idx * 512;
  for (int j = 0; j < 512; j++) acc += s_sc[j] * wr[j];
  mod[idx] = acc;
}

// ---------------- hn = LN(h)*(1+sc) + sm -> bf16 ----------------
__global__ __launch_bounds__(256) void st_ln(
    const float* __restrict__ h, const float* __restrict__ sm,
    const float* __restrict__ sc, unsigned short* __restrict__ hn) {
  int row = blockIdx.x * 4 + (threadIdx.x >> 6);
  int l = threadIdx.x & 63;
  const float4* hr = (const float4*)(h + (size_t)row * CDIM);
  float4 a = hr[l], b = hr[l + 64];
  float sum = a.x + a.y + a.z + a.w + b.x + b.y + b.z + b.w;
  float sq = a.x * a.x + a.y * a.y + a.z * a.z + a.w * a.w +
             b.x * b.x + b.y * b.y + b.z * b.z + b.w * b.w;
#pragma unroll
  for (int m = 1; m < 64; m <<= 1) {
    sum += __shfl_xor(sum, m, 64);
    sq += __shfl_xor(sq, m, 64);
  }
  float mean = sum * (1.0f / 512.0f);
  float var = sq * (1.0f / 512.0f) - mean * mean;
  float rs = rsqrtf(var + 1e-6f);
  const float4* sc4 = (const float4*)sc;
  const float4* sm4 = (const float4*)sm;
  float4 c0 = sc4[l], c1 = sc4[l + 64];
  float4 m0 = sm4[l], m1 = sm4[l + 64];
  ushort4 o0, o1;
  o0.x = f2bf((a.x - mean) * rs * (1.0f + c0.x) + m0.x);
  o0.y = f2bf((a.y - mean) * rs * (1.0f + c0.y) + m0.y);
  o0.z = f2bf((a.z - mean) * rs * (1.0f + c0.z) + m0.z);
  o0.w = f2bf((a.w - mean) * rs * (1.0f + c0.w) + m0.w);
  o1.x = f2bf((b.x - mean) * rs * (1.0f + c1.x) + m1.x);
  o1.y = f2bf((b.y - mean) * rs * (1.0f + c1.y) + m1.y);
  o1.z = f2bf((b.z - mean) * rs * (1.0f + c1.z) + m1.z);
  o1.w = f2bf((b.w - mean) * rs * (1.0f + c1.w) + m1.w);
  ushort4* out = (ushort4*)(hn + (size_t)row * CDIM);
  out[l] = o0;
  out[l + 64] = o1;
}

// ---------------- GEMM: C[M][Nout] = A[M][K]bf16 @ B[Nout][K]bf16^T ----------------
// 1D grid, id = bn*128 + bm  ->  all bn-tiles of one A row-block share an XCD
// (XCD = bm & 7) so A is fetched into that XCD's L2 once.
// EPI 0 (qkv): cols <512 scaled by 0.125*log2e -> bf16 big (Q);
//              cols 512..1023 -> bf16 big (K);
//              cols >=1024 (V): written ONLY to vt, f16, transposed+rolled:
//              vt[(wz*8+hh)*64+dd][j] with p=(row-shift)&NMASK, wz=p>>10,
//              j=p&1023 (j0%4==0 since shift%4==0 -> ushort4 store is safe).
// EPI 1: gelu(+bias) -> bf16 out
// EPI 2: h[row][col] += gate[col] * (acc + bias[col])   (fp32 residual)
template <int EPI>
__global__ __launch_bounds__(256, 2) void st_gemm(
    const unsigned short* __restrict__ A, const unsigned short* __restrict__ B,
    const float* __restrict__ bias, const float* __restrict__ gate,
    float* __restrict__ hbuf, unsigned short* __restrict__ outb,
    unsigned short* __restrict__ vt, int shift,
    int K, int Nout) {
  __shared__ __align__(16) unsigned short sA[128 * 64];
  __shared__ __align__(16) unsigned short sB[128 * 64];
  int tid = threadIdx.x;
  int wv = tid >> 6, l = tid & 63;
  int lr = l >> 3, lc = l & 7;
  int swz = (lc ^ lr) * 8;  // XOR swizzle (elems) baked into global read
  int bn = blockIdx.x >> 7, bm = blockIdx.x & 127;
  const unsigned short* Ab = A + (size_t)bm * 128 * K;
  const unsigned short* Bb = B + (size_t)bn * 128 * K;
  int wm = (wv >> 1) * 64, wn = (wv & 1) * 64;
  int lanem = l & 15, quad = l >> 4;
  f32x4 acc[4][4] = {};
  for (int k0 = 0; k0 < K; k0 += 64) {
#pragma unroll
    for (int ii = 0; ii < 4; ii++) {
      int row = wv * 32 + ii * 8 + lr;
      async16(&sA[row * 64 + lc * 8], Ab + (size_t)row * K + k0 + swz);
      async16(&sB[row * 64 + lc * 8], Bb + (size_t)row * K + k0 + swz);
    }
    __syncthreads();
#pragma unroll
    for (int kk = 0; kk < 2; kk++) {
      int q = quad + kk * 4;
      bf16x8 af[4], bfr[4];
#pragma unroll
      for (int mi = 0; mi < 4; mi++) {
        int r = wm + mi * 16 + lanem;
        af[mi] = *(const bf16x8*)&sA[r * 64 + ((q ^ (r & 7)) * 8)];
      }
#pragma unroll
      for (int ni = 0; ni < 4; ni++) {
        int r = wn + ni * 16 + lanem;
        bfr[ni] = *(const bf16x8*)&sB[r * 64 + ((q ^ (r & 7)) * 8)];
      }
#pragma unroll
      for (int mi = 0; mi < 4; mi++)
#pragma unroll
        for (int ni = 0; ni < 4; ni++)
          acc[mi][ni] = __builtin_amdgcn_mfma_f32_16x16x32_bf16(af[mi], bfr[ni], acc[mi][ni], 0, 0, 0);
    }
    __syncthreads();
  }
#pragma unroll
  for (int mi = 0; mi < 4; mi++) {
#pragma unroll
    for (int ni = 0; ni < 4; ni++) {
      int col = bn * 128 + wn + ni * 16 + lanem;
      float bv = bias[col];
      if (EPI == 0 && col >= 1024) {
        // V column: write transposed f16 into vt only
        int hh = (col - 1024) >> 6, dd = (col - 1024) & 63;
        int rowbase = bm * 128 + wm + mi * 16 + quad * 4;
        int p = (rowbase - shift) & NMASK;
        int wz = p >> 10, j0 = p & 1023;
        f16x2 lo = pk_f16(acc[mi][ni][0] + bv, acc[mi][ni][1] + bv);
        f16x2 hi = pk_f16(acc[mi][ni][2] + bv, acc[mi][ni][3] + bv);
        f16x4 v4 = __builtin_shufflevector(lo, hi, 0, 1, 2, 3);
        *(f16x4*)(vt + ((size_t)(wz * 8 + hh) * 64 + dd) * 1024 + j0) = v4;
        continue;
      }
      float qscale = (EPI == 0 && col < 512) ? 0.18033688f : 1.0f;
#pragma unroll
      for (int rg = 0; rg < 4; rg++) {
        int row = bm * 128 + wm + mi * 16 + quad * 4 + rg;
        float v = acc[mi][ni][rg] + bv;
        if (EPI == 0) {
          outb[(size_t)row * Nout + col] = f2bf(v * qscale);
        } else if (EPI == 1) {
          // tanh-approx gelu: x * sigmoid(2.3022082x + 0.10294326x^3), via exp2
          float arg = v * fmaf(0.10294326f, v * v, 2.3022082f);
          float g = v / (1.0f + exp2f(-arg));
          outb[(size_t)row * Nout + col] = f2bf(g);
        } else {
          size_t idx = (size_t)row * CDIM + col;
          hbuf[idx] = hbuf[idx] + gate[col] * v;
        }
      }
    }
  }
}

// ---------------- window attention v4 ----------------
// 1D grid 1024, id = qt*128 + hh*16 + wz  ->  XCD = wz & 7: all 8 qt-blocks of
// one (window,head) land on the same XCD so K/V is fetched into its L2 once.
// S^T = K·Q^T (Q pre-scaled by 0.125*log2e in the qkv GEMM epilogue) ->
// C-layout == B-operand layout of 16x16x16 f16 MFMA -> P packs in-register.
// Softmax denominator accumulated on the MFMA pipe via a ones-vector A-frag.
__global__ __launch_bounds__(256, 4) void st_attn(
    const unsigned short* __restrict__ qkv, const unsigned short* __restrict__ vt,
    unsigned short* __restrict__ ao, int shift) {
  __shared__ __align__(16) unsigned short sK[2][64 * 64];
  __shared__ __align__(16) unsigned short sV[2][64 * 64];
  int id = blockIdx.x;
  int qt = id >> 7, hh = (id >> 4) & 7, wz = id & 15;
  int tid = threadIdx.x;
  int wv = tid >> 6, l = tid & 63;
  int lanem = l & 15, quad = l >> 4;
  int wbase = wz * 1024;
  int qbase = wbase + qt * 128 + wv * 32;

  // Q fragments (B-operand layout for 16x16x32): lane n=i, k=d
  bf16x8 qf[2][2];
#pragma unroll
  for (int ni = 0; ni < 2; ni++) {
    int g = (qbase + ni * 16 + lanem + shift) & NMASK;
    const unsigned short* qp = qkv + (size_t)g * 1536 + hh * 64 + quad * 8;
    qf[ni][0] = *(const bf16x8*)qp;
    qf[ni][1] = *(const bf16x8*)(qp + 32);
  }
  const unsigned short* vbase = vt + (size_t)(wz * 8 + hh) * 64 * 1024;

  f32x4 oacc[4][2] = {};
  f32x4 osum[2] = {};
  f16x4 ones;
  ones[0] = (_Float16)1.0f; ones[1] = (_Float16)1.0f;
  ones[2] = (_Float16)1.0f; ones[3] = (_Float16)1.0f;

  // stage K-tile + V^T-tile kt into buffer b
  auto stage = [&](int b, int kt) {
#pragma unroll
    for (int ii = 0; ii < 2; ii++) {
      int chunk = ii * 256 + tid;
      int r = chunk >> 3, c = chunk & 7;
      int gk = (wbase + kt * 64 + r + shift) & NMASK;
      async16(&sK[b][chunk * 8], qkv + (size_t)gk * 1536 + 512 + hh * 64 + ((c ^ (r & 7)) * 8));
      async16(&sV[b][chunk * 8], vbase + (size_t)r * 1024 + kt * 64 + ((c ^ (r & 7)) * 8));
    }
  };

  stage(0, 0);
  int buf = 0;
  for (int kt = 0; kt < 16; kt++) {
    __syncthreads();  // drains staging vmcnt + protects buf^1 reuse
    if (kt < 15) stage(buf ^ 1, kt + 1);
    const unsigned short* Kb = &sK[buf][0];
    const unsigned short* Vb = &sV[buf][0];
#pragma unroll
    for (int mj = 0; mj < 4; mj++) {
      int r = mj * 16 + lanem;
      bf16x8 kf0 = *(const bf16x8*)&Kb[r * 64 + ((quad ^ (r & 7)) * 8)];
      bf16x8 kf1 = *(const bf16x8*)&Kb[r * 64 + (((4 + quad) ^ (r & 7)) * 8)];
      f16x4 vf[4];
#pragma unroll
      for (int dm = 0; dm < 4; dm++) {
        int d = dm * 16 + lanem;
        int phys = (((mj * 2 + (quad >> 1)) ^ (d & 7)) * 8) + (quad & 1) * 4;
        vf[dm] = *(const f16x4*)&Vb[d * 64 + phys];
      }
      f16x4 pf[2];
#pragma unroll
      for (int ni = 0; ni < 2; ni++) {
        f32x4 s = {};
        s = __builtin_amdgcn_mfma_f32_16x16x32_bf16(kf0, qf[ni][0], s, 0, 0, 0);
        s = __builtin_amdgcn_mfma_f32_16x16x32_bf16(kf1, qf[ni][1], s, 0, 0, 0);
        f16x2 lo = pk_f16(exp2f(s[0]), exp2f(s[1]));
        f16x2 hi = pk_f16(exp2f(s[2]), exp2f(s[3]));
        pf[ni] = __builtin_shufflevector(lo, hi, 0, 1, 2, 3);
        osum[ni] = __builtin_amdgcn_mfma_f32_16x16x16f16(ones, pf[ni], osum[ni], 0, 0, 0);
      }
#pragma unroll
      for (int dm = 0; dm < 4; dm++)
#pragma unroll
        for (int ni = 0; ni < 2; ni++)
          oacc[dm][ni] = __builtin_amdgcn_mfma_f32_16x16x16f16(vf[dm], pf[ni], oacc[dm][ni], 0, 0, 0);
    }
    buf ^= 1;
  }
#pragma unroll
  for (int ni = 0; ni < 2; ni++) {
    float inv = 1.0f / osum[ni][0];  // every C-row of the ones-MFMA == colsum
    int g = (qbase + ni * 16 + lanem + shift) & NMASK;
    unsigned short* orow = ao + (size_t)g * CDIM + hh * 64;
#pragma unroll
    for (int dm = 0; dm < 4; dm++) {
      ushort4 o;
      o.x = f2bf(oacc[dm][ni][0] * inv);
      o.y = f2bf(oacc[dm][ni][1] * inv);
      o.z = f2bf(oacc[dm][ni][2] * inv);
      o.w = f2bf(oacc[dm][ni][3] * inv);
      *(ushort4*)(orow + dm * 16 + quad * 4) = o;
    }
  }
}

// ---------------- out = h @ out_w^T + out_b (fp32) ----------------
__global__ __launch_bounds__(128) void st_outproj(
    const float* __restrict__ h, const float* __restrict__ out_w,
    const float* __restrict__ out_b, float* __restrict__ out) {
  __shared__ float sh[16 * 513];
  __shared__ float sw[8 * 520];
  int tid = threadIdx.x;
  int rbase = blockIdx.x * 16;
  for (int i = tid; i < 16 * 512; i += 128) {
    int r = i >> 9, c = i & 511;
    sh[r * 513 + c] = h[(size_t)(rbase + r) * 512 + c];
  }
  for (int i = tid; i < 8 * 512; i += 128) {
    int r = i >> 9, c = i & 511;
    sw[r * 520 + c] = out_w[i];
  }
  __syncthreads();
  int r = tid >> 3, co = tid & 7;
  float acc = out_b[co];
  const float* hr = sh + r * 513;
  const float* wr = sw + co * 520;
  for (int c = 0; c < 512; c++) acc += hr[c] * wr[c];
  out[(size_t)(rbase + r) * 8 + co] = acc;
}

extern "C" void kernel_launch(void* const* d_in, const int* in_sizes, int n_in,
                              void* d_out, int out_size, void* d_ws, size_t ws_size,
                              hipStream_t stream) {
  const float* feats = (const float*)d_in[0];
  const int* coords = (const int*)d_in[1];
  const float* tptr = (const float*)d_in[2];
  const float* in_w = (const float*)d_in[3];
  const float* in_b = (const float*)d_in[4];
  const float* t_w1 = (const float*)d_in[5];
  const float* t_b1 = (const float*)d_in[6];
  const float* t_w2 = (const float*)d_in[7];
  const float* t_b2 = (const float*)d_in[8];
  const float* qkv_w = (const float*)d_in[9];
  const float* qkv_b = (const float*)d_in[10];
  const float* proj_w = (const float*)d_in[11];
  const float* proj_b = (const float*)d_in[12];
  const float* ada_w = (const float*)d_in[13];
  const float* ada_b = (const float*)d_in[14];
  const float* fc1_w = (const float*)d_in[15];
  const float* fc1_b = (const float*)d_in[16];
  const float* fc2_w = (const float*)d_in[17];
  const float* fc2_b = (const float*)d_in[18];
  const float* out_w = (const float*)d_in[19];
  const float* out_b = (const float*)d_in[20];
  float* out = (float*)d_out;

  char* ws = (char*)d_ws;
  size_t off = 0;
  auto alloc = [&](size_t bytes) {
    char* p = ws + off;
    off += (bytes + 255) & ~(size_t)255;
    return p;
  };
  unsigned short* w_qkv = (unsigned short*)alloc((size_t)8 * 1536 * 512 * 2);
  unsigned short* w_proj = (unsigned short*)alloc((size_t)8 * 512 * 512 * 2);
  unsigned short* w_fc1 = (unsigned short*)alloc((size_t)8 * 2048 * 512 * 2);
  unsigned short* w_fc2 = (unsigned short*)alloc((size_t)8 * 512 * 2048 * 2);
  float* h = (float*)alloc((size_t)NTOK * 512 * 4);
  unsigned short* hn = (unsigned short*)alloc((size_t)NTOK * 512 * 2);
  unsigned short* big = (unsigned short*)alloc((size_t)NTOK * 2048 * 2);  // qkv, then ffn-mid
  unsigned short* ao = (unsigned short*)alloc((size_t)NTOK * 512 * 2);
  unsigned short* vtb = (unsigned short*)alloc((size_t)16 * 8 * 64 * 1024 * 2);
  float* cbuf = (float*)alloc(512 * 4);
  float* mod = (float*)alloc((size_t)8 * 3072 * 4);
  if (ws_size < off) return;  // insufficient workspace -> fail loudly at validation

  st_cvt_bf16<<<512, 256, 0, stream>>>((const float4*)qkv_w, (ushort4*)w_qkv, 8 * 1536 * 512 / 4);
  st_cvt_bf16<<<512, 256, 0, stream>>>((const float4*)proj_w, (ushort4*)w_proj, 8 * 512 * 512 / 4);
  st_cvt_bf16<<<512, 256, 0, stream>>>((const float4*)fc1_w, (ushort4*)w_fc1, 8 * 2048 * 512 / 4);
  st_cvt_bf16<<<512, 256, 0, stream>>>((const float4*)fc2_w, (ushort4*)w_fc2, 8 * 512 * 2048 / 4);
  st_embed<<<NTOK, 512, 0, stream>>>(feats, coords, in_w, in_b, h);
  st_tembed1<<<1, 512, 0, stream>>>(tptr, t_w1, t_b1, t_w2, t_b2, cbuf);
  st_tembed2<<<96, 256, 0, stream>>>(cbuf, ada_w, ada_b, mod);

  for (int i = 0; i < 8; i++) {
    int shift = (i & 1) ? 512 : 0;
    const float* modl = mod + i * 3072;
    // attn branch (V-transpose fused into the qkv GEMM epilogue)
    st_ln<<<4096, 256, 0, stream>>>(h, modl, modl + 512, hn);
    st_gemm<0><<<12 * 128, 256, 0, stream>>>(hn, w_qkv + (size_t)i * 1536 * 512,
                                             qkv_b + i * 1536, nullptr, nullptr, big,
                                             vtb, shift, 512, 1536);
    st_attn<<<8 * 128, 256, 0, stream>>>(big, vtb, ao, shift);
    st_gemm<2><<<4 * 128, 256, 0, stream>>>(ao, w_proj + (size_t)i * 512 * 512,
                                            proj_b + i * 512, modl + 1024, h, nullptr,
                                            nullptr, 0, 512, 512);
    // mlp branch
    st_ln<<<4096, 256, 0, stream>>>(h, modl + 1536, modl + 2048, hn);
    st_gemm<1><<<16 * 128, 256, 0, stream>>>(hn, w_fc1 + (size_t)i * 2048 * 512,
                                             fc1_b + i * 2048, nullptr, nullptr, big,
                                             nullptr, 0, 512, 2048);
    st_gemm<2><<<4 * 128, 256, 0, stream>>>(big, w_fc2 + (size_t)i * 512 * 2048,
                                            fc2_b + i * 512, modl + 2560, h, nullptr,
                                            nullptr, 0, 2048, 512);
  }
  st_outproj<<<1024, 128, 0, stream>>>(h, out_w, out_b, out);
}